// Round 20
// baseline (113.510 us; speedup 1.0000x reference)
//
#include <hip/hip_runtime.h>
#include <math.h>

#define BB 8
#define TT 16384
#define DD 128
#define DH 64
#define FMARGIN 0.05f

typedef _Float16 half8 __attribute__((ext_vector_type(8)));
typedef float f32x4 __attribute__((ext_vector_type(4)));

union H8 { half8 h; uint4 q; ushort us[8]; };

static __device__ __forceinline__ float4 ld4(const float* p) { return *(const float4*)p; }

// pack two floats as adjacent fp16 in a u32 (low = first)
static __device__ __forceinline__ uint pk2(float a, float b) {
    union { _Float16 f; ushort u; } A, B;
    A.f = (_Float16)a; B.f = (_Float16)b;
    return (uint)A.u | ((uint)B.u << 16);
}

// split 8 fp32 -> fp16 hi + fp16 lo (x = hi + lo exact to ~2^-22)
static __device__ __forceinline__ void split8h(const float4 v0, const float4 v1,
                                               half8* xh, half8* xl)
{
    float f[8] = {v0.x, v0.y, v0.z, v0.w, v1.x, v1.y, v1.z, v1.w};
    half8 h, l;
    #pragma unroll
    for (int j = 0; j < 8; ++j) {
        _Float16 hv = (_Float16)f[j];
        h[j] = hv;
        l[j] = (_Float16)(f[j] - (float)hv);
    }
    *xh = h; *xl = l;
}

// ---------------------------------------------------------------------------
// Kernel W-prep: weights fp32 -> fp16 MFMA B-fragment layout (single fp16).
// ---------------------------------------------------------------------------
__global__ __launch_bounds__(64) void k_wprep(
    const float* __restrict__ Wa1, const float* __restrict__ Wa2,
    const float* __restrict__ Wd, const float* __restrict__ Wk,
    const float* __restrict__ Wq, ushort* __restrict__ wfm,
    ushort* __restrict__ wfb)
{
    const int l  = threadIdx.x;
    const int nt = blockIdx.x & 7;
    const int kb = blockIdx.x >> 3;
    const int ly = blockIdx.y;
    const int n  = nt * 16 + (l & 15);
    const int k0 = kb * 32 + (l >> 4) * 8;
    H8 v;
    if (ly < 3) {
        const float* W = (ly == 0) ? Wa1 : (ly == 1) ? Wa2 : Wd;
        #pragma unroll
        for (int e = 0; e < 8; ++e) v.h[e] = (_Float16)W[(k0 + e) * DD + n];
        *(uint4*)(wfm + (size_t)(((ly * 8 + nt) * 4 + kb) * 64 + l) * 8) = v.q;
    } else {
        #pragma unroll
        for (int e = 0; e < 8; ++e) {
            float w = (n < 64) ? Wk[(k0 + e) * DH + n] : Wq[(k0 + e) * DH + n - 64];
            v.h[e] = (_Float16)w;
        }
        *(uint4*)(wfb + (size_t)((nt * 4 + kb) * 64 + l) * 8) = v.q;
    }
}

// ---------------------------------------------------------------------------
// Kernel 1: binding logits via fp16 MFMA, 2-product, inline fp32 fixup.
// (r19 version: launch_bounds(256,4) + async B DMA — took it off the top-5)
// ---------------------------------------------------------------------------
__global__ __launch_bounds__(256, 4) void k_bind(
    const float* __restrict__ x, const ushort* __restrict__ wfb,
    const float* __restrict__ Wk, const float* __restrict__ Wq,
    const float* __restrict__ bk, const float* __restrict__ bq,
    int* __restrict__ cstart)
{
    __shared__ uint4 Bs4[2048];
    __shared__ float bnd[4][64];
    const int b    = blockIdx.y;
    const int tb   = blockIdx.x * 64;
    const int tid  = threadIdx.x;
    const int wv   = tid >> 6;
    const int l    = tid & 63;
    const int lo16 = l & 15;
    const int g    = l >> 4;

    {
        const uint4* wsrc = (const uint4*)wfb;
        #pragma unroll
        for (int j = 0; j < 8; ++j) {
            int idx = tid + j * 256;
            __builtin_amdgcn_global_load_lds(
                (const __attribute__((address_space(1))) void*)(wsrc + idx),
                (__attribute__((address_space(3))) void*)&Bs4[idx], 16, 0, 0);
        }
    }

    const float* xrow = x + ((size_t)b * TT + tb + wv * 16 + lo16) * DD;
    half8 xh[4], xl[4];
    #pragma unroll
    for (int kb = 0; kb < 4; ++kb) {
        float4 v0 = ld4(xrow + kb * 32 + g * 8);
        float4 v1 = ld4(xrow + kb * 32 + g * 8 + 4);
        split8h(v0, v1, &xh[kb], &xl[kb]);
    }
    int r64 = tb + 64; if (r64 > TT - 1) r64 = TT - 1;
    const float* xq = x + ((size_t)b * TT + r64) * DD;
    half8 qh[4], ql[4];
    H8 z; z.q.x = z.q.y = z.q.z = z.q.w = 0u;
    #pragma unroll
    for (int kb = 0; kb < 4; ++kb) {
        qh[kb] = z.h; ql[kb] = z.h;
        if (lo16 == 0) {
            float4 v0 = ld4(xq + kb * 32 + g * 8);
            float4 v1 = ld4(xq + kb * 32 + g * 8 + 4);
            split8h(v0, v1, &qh[kb], &ql[kb]);
        }
    }

    f32x4 acc[8];
    #pragma unroll
    for (int nt = 0; nt < 8; ++nt) {
        int col = nt * 16 + lo16;
        float bias = (col < 64) ? bk[col] : bq[col - 64];
        acc[nt] = (f32x4){bias, bias, bias, bias};
    }
    f32x4 acc4;
    {
        float bias = bq[wv * 16 + lo16];
        acc4 = (f32x4){bias, bias, bias, bias};
    }

    asm volatile("s_waitcnt vmcnt(0)" ::: "memory");
    __syncthreads();
    const ushort* Bs = (const ushort*)Bs4;
    const ushort* Bs_halo = Bs + (size_t)((4 + wv) * 4 * 64 + l) * 8;
    #pragma unroll
    for (int kb = 0; kb < 4; ++kb) {
        half8 bh[8];
        #pragma unroll
        for (int nt = 0; nt < 8; ++nt)
            bh[nt] = *(const half8*)(Bs + (size_t)((nt * 4 + kb) * 64 + l) * 8);
        #pragma unroll
        for (int nt = 0; nt < 8; ++nt) {
            acc[nt] = __builtin_amdgcn_mfma_f32_16x16x32_f16(xh[kb], bh[nt], acc[nt], 0, 0, 0);
            acc[nt] = __builtin_amdgcn_mfma_f32_16x16x32_f16(xl[kb], bh[nt], acc[nt], 0, 0, 0);
        }
        half8 bh4 = *(const half8*)(Bs_halo + (size_t)kb * 64 * 8);
        acc4 = __builtin_amdgcn_mfma_f32_16x16x32_f16(qh[kb], bh4, acc4, 0, 0, 0);
        acc4 = __builtin_amdgcn_mfma_f32_16x16x32_f16(ql[kb], bh4, acc4, 0, 0, 0);
    }

    if (l < 16) {
        if (wv > 0) {
            #pragma unroll
            for (int nt = 0; nt < 4; ++nt) bnd[wv - 1][nt * 16 + lo16] = acc[4 + nt][0];
        }
        bnd[3][wv * 16 + lo16] = acc4[0];
    }
    __syncthreads();

    float qn3[4];
    #pragma unroll
    for (int nt = 0; nt < 4; ++nt) qn3[nt] = __shfl_down(acc[4 + nt][0], 16);
    if (g == 3) {
        #pragma unroll
        for (int nt = 0; nt < 4; ++nt) qn3[nt] = bnd[wv][nt * 16 + lo16];
    }
    float s[4];
    #pragma unroll
    for (int i = 0; i < 3; ++i) {
        float t = 0.f;
        #pragma unroll
        for (int nt = 0; nt < 4; ++nt) t += acc[nt][i] * acc[4 + nt][i + 1];
        s[i] = t;
    }
    {
        float t = 0.f;
        #pragma unroll
        for (int nt = 0; nt < 4; ++nt) t += acc[nt][3] * qn3[nt];
        s[3] = t;
    }
    #pragma unroll
    for (int i = 0; i < 4; ++i) {
        #pragma unroll
        for (int m = 1; m < 16; m <<= 1) s[i] += __shfl_xor(s[i], m);
    }

    #pragma unroll
    for (int i = 0; i < 4; ++i) {
        int t = tb + wv * 16 + g * 4 + i;
        bool valid = (lo16 == 0) && (t <= TT - 2);
        bool border = valid && (fabsf(s[i]) < FMARGIN);
        if (valid && !border) cstart[b * TT + t + 1] = (s[i] > 0.f) ? 0 : 1;
        unsigned long long m = __ballot(border);
        while (m) {
            int src = __ffsll((long long)m) - 1;
            m &= m - 1;
            int tf = tb + wv * 16 + (src >> 4) * 4 + i;
            const float* xt = x + ((size_t)b * TT + tf) * DD;
            float K = bk[l], Q = bq[l];
            #pragma unroll 8
            for (int k2 = 0; k2 < DD; ++k2) {
                K = fmaf(xt[k2],      Wk[k2 * DH + l], K);
                Q = fmaf(xt[DD + k2], Wq[k2 * DH + l], Q);
            }
            float p = K * Q;
            #pragma unroll
            for (int m2 = 1; m2 < 64; m2 <<= 1) p += __shfl_xor(p, m2);
            if (l == 0) cstart[b * TT + tf + 1] = (p > 0.f) ? 0 : 1;
        }
    }
    if (blockIdx.x == 0 && tid == 0) cstart[b * TT] = 1;
}

// ---------------------------------------------------------------------------
// Kernel 2: per-batch scan -> seg, chunk-start table, counts. (unchanged)
// ---------------------------------------------------------------------------
__global__ __launch_bounds__(1024) void k_scan(const int* __restrict__ cstart,
    int* __restrict__ seg, int* __restrict__ cs, int* __restrict__ numC)
{
    __shared__ int wsum[16];
    const int b = blockIdx.x, tid = threadIdx.x;
    const int wv = tid >> 6, lane = tid & 63;
    const int base = b * TT + tid * 16;
    int v[16];
    #pragma unroll
    for (int i = 0; i < 4; ++i) {
        int4 q = *(const int4*)(cstart + base + i * 4);
        v[i * 4 + 0] = q.x; v[i * 4 + 1] = q.y; v[i * 4 + 2] = q.z; v[i * 4 + 3] = q.w;
    }
    int s[16]; int run = 0;
    #pragma unroll
    for (int i = 0; i < 16; ++i) { run += v[i]; s[i] = run; }
    int incl = run;
    #pragma unroll
    for (int off = 1; off < 64; off <<= 1) {
        int t = __shfl_up(incl, off);
        if (lane >= off) incl += t;
    }
    if (lane == 63) wsum[wv] = incl;
    __syncthreads();
    if (tid < 16) {
        int w = wsum[tid];
        #pragma unroll
        for (int off = 1; off < 16; off <<= 1) {
            int t = __shfl_up(w, off, 16);
            if (tid >= off) w += t;
        }
        wsum[tid] = w;
    }
    __syncthreads();
    const int excl = (wv ? wsum[wv - 1] : 0) + incl - run;
    #pragma unroll
    for (int i = 0; i < 16; ++i) {
        int sg = excl + s[i] - 1;
        seg[base + i] = sg;
        if (v[i]) cs[b * (TT + 1) + sg] = tid * 16 + i;
    }
    if (tid == 1023) {
        int tot = excl + run;
        numC[b] = tot;
        cs[b * (TT + 1) + tot] = TT;
    }
}

// ---------------------------------------------------------------------------
// k_mlp GEMM: acc[8] = A(fp16 frags in LDS) @ B(fp16 frags in LDS).
// ---------------------------------------------------------------------------
__device__ __forceinline__ void mlp_gemm(f32x4 acc[8], const uint4* Afr4,
    const ushort* Bs, int wv, int l)
{
    half8 af[4];
    #pragma unroll
    for (int kb = 0; kb < 4; ++kb)
        af[kb] = *(const half8*)((const char*)Afr4 + ((wv * 4 + kb) * 64 + l) * 16);
    #pragma unroll
    for (int kb = 0; kb < 4; ++kb) {
        half8 bh[8];
        #pragma unroll
        for (int nt = 0; nt < 8; ++nt)
            bh[nt] = *(const half8*)(Bs + (size_t)((nt * 4 + kb) * 64 + l) * 8);
        #pragma unroll
        for (int nt = 0; nt < 8; ++nt)
            acc[nt] = __builtin_amdgcn_mfma_f32_16x16x32_f16(af[kb], bh[nt], acc[nt], 0, 0, 0);
    }
}

// ---------------------------------------------------------------------------
// Kernel 3: per-chunk MLP via fp16 MFMA. r20: 32 CHUNKS/BLOCK (r12's split,
// re-run WITHOUT its fp16-gate write-amplification bug): 2048 active blocks,
// LDS union 40960B -> 4 blocks/CU, per-block critical path halves (avg 2
// token-tiles, half the GEMM). Waves 0-1 do GEMM/LN (32 rows = 2x16-row
// tiles); all waves stage/DMA. Gate fp32 -> cm (sector-aligned). Keeps the
// r15 async tile DMA + r17 async B-layer DMAs.
// ---------------------------------------------------------------------------
__global__ __launch_bounds__(256, 2) void k_mlp(
    const float* __restrict__ x, const int* __restrict__ cs,
    const float* __restrict__ ba1, const float* __restrict__ ln_g, const float* __restrict__ ln_b,
    const float* __restrict__ ba2, const float* __restrict__ bd,
    const ushort* __restrict__ wfm, const int* __restrict__ numC, float* __restrict__ cm)
{
    __shared__ union {
        float Tok[2][32 * 128];                            // 2 x 16384 B (UNPADDED: DMA dest)
        struct { uint4 Afr[512]; uint4 Bs[2048]; } fb;     // 40960 B frags
    } sm;
    const int b  = blockIdx.y;
    const int nC = numC[b];
    const int c0 = blockIdx.x * 32;
    if (c0 >= nC) return;
    const int tid  = threadIdx.x;
    const int wv   = tid >> 6;
    const int l    = tid & 63;
    const int lo16 = l & 15;
    const int g    = l >> 4;
    const ushort* Bs = (const ushort*)sm.fb.Bs;
    const uint4* wsrc = (const uint4*)wfm;

    // ---- phase 1: chunk means, async double-buffered 32-token tiles ----
    const int cbase = b * (TT + 1);
    const int T0 = cs[cbase + c0];
    const int cEnd = (c0 + 32 < nC) ? (c0 + 32) : nC;
    const int T1 = cs[cbase + cEnd];
    int t0r[4], t1r[4];
    #pragma unroll
    for (int ii = 0; ii < 4; ++ii) {
        int r = (tid + ii * 256) >> 5;      // r in [0,32)
        int c = c0 + r;
        t0r[ii] = (c < nC) ? cs[cbase + c] : 0;
        t1r[ii] = (c < nC) ? cs[cbase + c + 1] : 0;
    }
    float4 vals[4];
    #pragma unroll
    for (int ii = 0; ii < 4; ++ii) vals[ii] = make_float4(0.f, 0.f, 0.f, 0.f);

    // prologue: async-stage tile 0 into Tok[0]
    {
        const int n16 = ((T0 + 32 < T1) ? 32 : (T1 - T0)) * 32;
        #pragma unroll
        for (int j = 0; j < 4; ++j) {
            int base16 = j * 256 + wv * 64;
            if (base16 + l < n16) {
                const float* gs = x + ((size_t)b * TT + T0) * DD + (size_t)(base16 + l) * 4;
                __builtin_amdgcn_global_load_lds(
                    (const __attribute__((address_space(1))) void*)gs,
                    (__attribute__((address_space(3))) void*)&sm.Tok[0][base16 * 4],
                    16, 0, 0);
            }
        }
    }
    int buf = 0;
    for (int tt = T0; tt < T1; tt += 32) {
        asm volatile("s_waitcnt vmcnt(0)" ::: "memory");
        __syncthreads();
        const int tEnd = (tt + 32 < T1) ? (tt + 32) : T1;
        if (tt + 32 < T1) {
            const int nEnd = (tt + 64 < T1) ? (tt + 64) : T1;
            const int n16 = (nEnd - (tt + 32)) * 32;
            #pragma unroll
            for (int j = 0; j < 4; ++j) {
                int base16 = j * 256 + wv * 64;
                if (base16 + l < n16) {
                    const float* gs = x + ((size_t)b * TT + tt + 32) * DD + (size_t)(base16 + l) * 4;
                    __builtin_amdgcn_global_load_lds(
                        (const __attribute__((address_space(1))) void*)gs,
                        (__attribute__((address_space(3))) void*)&sm.Tok[buf ^ 1][base16 * 4],
                        16, 0, 0);
                }
            }
        }
        #pragma unroll
        for (int ii = 0; ii < 4; ++ii) {
            int c4 = ((tid + ii * 256) & 31) * 4;
            int lo = (t0r[ii] > tt)   ? t0r[ii] : tt;
            int hi = (t1r[ii] < tEnd) ? t1r[ii] : tEnd;
            for (int t = lo; t < hi; ++t) {
                const float* ap = &sm.Tok[buf][(t - tt) * 128 + c4];
                vals[ii].x += ap[0]; vals[ii].y += ap[1];
                vals[ii].z += ap[2]; vals[ii].w += ap[3];
            }
        }
        buf ^= 1;
    }
    asm volatile("s_waitcnt vmcnt(0)" ::: "memory");
    __syncthreads();                           // Tok dies; union flips to frags

    // issue B0 DMA (overlaps the A-frag pack below)
    #pragma unroll
    for (int j = 0; j < 8; ++j) {
        int idx = tid + j * 256;
        __builtin_amdgcn_global_load_lds(
            (const __attribute__((address_space(1))) void*)(wsrc + idx),
            (__attribute__((address_space(3))) void*)&sm.fb.Bs[idx], 16, 0, 0);
    }
    // divide means, pack fp16 A-frags (rows 0..31 -> frags 0..7)
    #pragma unroll
    for (int ii = 0; ii < 4; ++ii) {
        int i = tid + ii * 256;
        int r = i >> 5, c4 = (i & 31) * 4;
        float4 sv = make_float4(0.f, 0.f, 0.f, 0.f);
        if (c0 + r < nC) {
            float inv = 1.f / (float)(t1r[ii] - t0r[ii]);
            sv.x = vals[ii].x * inv; sv.y = vals[ii].y * inv;
            sv.z = vals[ii].z * inv; sv.w = vals[ii].w * inv;
        }
        int frag = (r >> 4) * 4 + (c4 >> 5);
        int lanef = (r & 15) + (((c4 & 31) >> 3) * 16);
        uint2 pk = make_uint2(pk2(sv.x, sv.y), pk2(sv.z, sv.w));
        *(uint2*)((char*)sm.fb.Afr + frag * 1024 + lanef * 16 + (c4 & 7) * 2) = pk;
    }
    asm volatile("s_waitcnt vmcnt(0)" ::: "memory");
    __syncthreads();

    // ---- layer 1 (waves 0-1): h = cm @ Wa1 + ba1; LayerNorm; ReLU ----
    f32x4 acc[8];
    float mu_[4], rs_[4], gam[8], bet[8];
    if (wv < 2) {
        #pragma unroll
        for (int nt = 0; nt < 8; ++nt) {
            float bias = ba1[nt * 16 + lo16];
            acc[nt] = (f32x4){bias, bias, bias, bias};
        }
        mlp_gemm(acc, sm.fb.Afr, Bs, wv, l);
        #pragma unroll
        for (int i = 0; i < 4; ++i) {
            float smv = 0.f;
            #pragma unroll
            for (int nt = 0; nt < 8; ++nt) smv += acc[nt][i];
            #pragma unroll
            for (int k = 1; k < 16; k <<= 1) smv += __shfl_xor(smv, k, 16);
            mu_[i] = smv * (1.f / 128.f);
            float vs = 0.f;
            #pragma unroll
            for (int nt = 0; nt < 8; ++nt) { float d = acc[nt][i] - mu_[i]; vs += d * d; }
            #pragma unroll
            for (int k = 1; k < 16; k <<= 1) vs += __shfl_xor(vs, k, 16);
            rs_[i] = rsqrtf(vs * (1.f / 128.f) + 1e-5f);
        }
        #pragma unroll
        for (int nt = 0; nt < 8; ++nt) { gam[nt] = ln_g[nt * 16 + lo16]; bet[nt] = ln_b[nt * 16 + lo16]; }
    }
    __syncthreads();   // layer-1 A/B reads done
    // issue B1 DMA (all waves; overlaps the A-frag writes below)
    #pragma unroll
    for (int j = 0; j < 8; ++j) {
        int idx = tid + j * 256;
        __builtin_amdgcn_global_load_lds(
            (const __attribute__((address_space(1))) void*)(wsrc + 2048 + idx),
            (__attribute__((address_space(3))) void*)&sm.fb.Bs[idx], 16, 0, 0);
    }
    if (wv < 2) {
        #pragma unroll
        for (int nt = 0; nt < 8; ++nt) {
            int cw = nt * 16 + lo16;
            int frag = wv * 4 + (cw >> 5);
            int lnf  = (((cw & 31) >> 3) * 16);
            #pragma unroll
            for (int i = 0; i < 4; ++i) {
                float h = fmaf((acc[nt][i] - mu_[i]) * rs_[i], gam[nt], bet[nt]);
                union { _Float16 f; ushort u; } cv; cv.f = (_Float16)fmaxf(h, 0.f);
                *((ushort*)((char*)sm.fb.Afr + frag * 1024 + ((g * 4 + i) + lnf) * 16 + (cw & 7) * 2)) = cv.u;
            }
        }
    }
    asm volatile("s_waitcnt vmcnt(0)" ::: "memory");
    __syncthreads();

    // ---- layer 2 (waves 0-1): agg = relu(h) @ Wa2 + ba2 ----
    if (wv < 2) {
        #pragma unroll
        for (int nt = 0; nt < 8; ++nt) {
            float bias = ba2[nt * 16 + lo16];
            acc[nt] = (f32x4){bias, bias, bias, bias};
        }
        mlp_gemm(acc, sm.fb.Afr, Bs, wv, l);
    }
    __syncthreads();   // layer-2 A/B reads done
    // issue B2 DMA (all waves)
    #pragma unroll
    for (int j = 0; j < 8; ++j) {
        int idx = tid + j * 256;
        __builtin_amdgcn_global_load_lds(
            (const __attribute__((address_space(1))) void*)(wsrc + 4096 + idx),
            (__attribute__((address_space(3))) void*)&sm.fb.Bs[idx], 16, 0, 0);
    }
    if (wv < 2) {
        #pragma unroll
        for (int nt = 0; nt < 8; ++nt) {
            int cw = nt * 16 + lo16;
            int frag = wv * 4 + (cw >> 5);
            int lnf  = (((cw & 31) >> 3) * 16);
            #pragma unroll
            for (int i = 0; i < 4; ++i) {
                union { _Float16 f; ushort u; } cv; cv.f = (_Float16)acc[nt][i];
                *((ushort*)((char*)sm.fb.Afr + frag * 1024 + ((g * 4 + i) + lnf) * 16 + (cw & 7) * 2)) = cv.u;
            }
        }
    }
    asm volatile("s_waitcnt vmcnt(0)" ::: "memory");
    __syncthreads();

    // ---- layer 3 (waves 0-1): infl = agg @ Wd + bd; gate = sigmoid -> cm ----
    if (wv < 2) {
        #pragma unroll
        for (int nt = 0; nt < 8; ++nt) {
            float bias = bd[nt * 16 + lo16];
            acc[nt] = (f32x4){bias, bias, bias, bias};
        }
        mlp_gemm(acc, sm.fb.Afr, Bs, wv, l);
        #pragma unroll
        for (int i = 0; i < 4; ++i) {
            int row = c0 + wv * 16 + g * 4 + i;
            if (row < nC) {
                float* dst = cm + ((size_t)b * TT + row) * DD + lo16;
                #pragma unroll
                for (int nt = 0; nt < 8; ++nt)
                    dst[nt * 16] = 1.f / (1.f + __expf(-acc[nt][i]));
            }
        }
    }
}

// ---------------------------------------------------------------------------
// Kernel 4: out[t] = fma(x[t], gate[seg[t]], x[t])
// ---------------------------------------------------------------------------
__global__ __launch_bounds__(256) void k_out(const float* __restrict__ x,
    const int* __restrict__ seg, const float* __restrict__ gate, float* __restrict__ out)
{
    const size_t idx = (size_t)blockIdx.x * 256 + threadIdx.x;
    const size_t tok = idx >> 5;
    const int d4 = (int)(idx & 31);
    const int b  = (int)(tok >> 14);
    const int sg = seg[tok];
    float4 gv = ld4(gate + (((size_t)b << 14) + sg) * DD + d4 * 4);
    float4 xv = ld4(x + tok * DD + (size_t)d4 * 4);
    float4 o;
    o.x = fmaf(xv.x, gv.x, xv.x);
    o.y = fmaf(xv.y, gv.y, xv.y);
    o.z = fmaf(xv.z, gv.z, xv.z);
    o.w = fmaf(xv.w, gv.w, xv.w);
    *(float4*)(out + idx * 4) = o;
}

extern "C" void kernel_launch(void* const* d_in, const int* in_sizes, int n_in,
                              void* d_out, int out_size, void* d_ws, size_t ws_size,
                              hipStream_t stream)
{
    (void)in_sizes; (void)n_in; (void)out_size; (void)ws_size;
    const float* x    = (const float*)d_in[0];
    const float* Wk   = (const float*)d_in[1];
    const float* bk   = (const float*)d_in[2];
    const float* Wq   = (const float*)d_in[3];
    const float* bq   = (const float*)d_in[4];
    const float* Wa1  = (const float*)d_in[5];
    const float* ba1  = (const float*)d_in[6];
    const float* ln_g = (const float*)d_in[7];
    const float* ln_b = (const float*)d_in[8];
    const float* Wa2  = (const float*)d_in[9];
    const float* ba2  = (const float*)d_in[10];
    const float* Wd   = (const float*)d_in[11];
    const float* bd   = (const float*)d_in[12];
    float* out = (float*)d_out;

    // ws layout
    char* p = (char*)d_ws;
    float* cm    = (float*)p;   p += (size_t)BB * TT * DD * 4;   // 64 MB (gate)
    int* seg     = (int*)p;     p += (size_t)BB * TT * 4;        // bind bits -> seg ids
    int* cs      = (int*)p;     p += (size_t)BB * (TT + 1) * 4;
    int* numC    = (int*)p;     p += 64;
    ushort* wfm  = (ushort*)p;  p += 3 * DD * DD * 2;            // MLP W frags fp16 (96 KB)
    ushort* wfb  = (ushort*)p;  p += DD * DD * 2;                // bind W frags fp16 (32 KB)

    k_wprep<<<dim3(32, 4), 64, 0, stream>>>(Wa1, Wa2, Wd, Wk, Wq, wfm, wfb);
    k_bind<<<dim3(256, BB), 256, 0, stream>>>(x, wfb, Wk, Wq, bk, bq, seg);
    k_scan<<<dim3(BB), 1024, 0, stream>>>(seg, seg, cs, numC);
    k_mlp<<<dim3(TT / 32, BB), 256, 0, stream>>>(x, cs, ba1, ln_g, ln_b, ba2, bd, wfm, numC, cm);
    k_out<<<dim3(BB * TT * DD / (256 * 4)), 256, 0, stream>>>(x, seg, cm, out);
}

// Round 21
// 110.886 us; speedup vs baseline: 1.0237x; 1.0237x over previous
//
#include <hip/hip_runtime.h>
#include <math.h>

#define BB 8
#define TT 16384
#define DD 128
#define DH 64
#define FMARGIN 0.05f

typedef _Float16 half8 __attribute__((ext_vector_type(8)));
typedef float f32x4 __attribute__((ext_vector_type(4)));

union H8 { half8 h; uint4 q; ushort us[8]; };

static __device__ __forceinline__ float4 ld4(const float* p) { return *(const float4*)p; }

// pack two floats as adjacent fp16 in a u32 (low = first)
static __device__ __forceinline__ uint pk2(float a, float b) {
    union { _Float16 f; ushort u; } A, B;
    A.f = (_Float16)a; B.f = (_Float16)b;
    return (uint)A.u | ((uint)B.u << 16);
}

// split 8 fp32 -> fp16 hi + fp16 lo (x = hi + lo exact to ~2^-22)
static __device__ __forceinline__ void split8h(const float4 v0, const float4 v1,
                                               half8* xh, half8* xl)
{
    float f[8] = {v0.x, v0.y, v0.z, v0.w, v1.x, v1.y, v1.z, v1.w};
    half8 h, l;
    #pragma unroll
    for (int j = 0; j < 8; ++j) {
        _Float16 hv = (_Float16)f[j];
        h[j] = hv;
        l[j] = (_Float16)(f[j] - (float)hv);
    }
    *xh = h; *xl = l;
}

// ---------------------------------------------------------------------------
// Kernel W-prep: weights fp32 -> fp16 MFMA B-fragment layout (single fp16).
// ---------------------------------------------------------------------------
__global__ __launch_bounds__(64) void k_wprep(
    const float* __restrict__ Wa1, const float* __restrict__ Wa2,
    const float* __restrict__ Wd, const float* __restrict__ Wk,
    const float* __restrict__ Wq, ushort* __restrict__ wfm,
    ushort* __restrict__ wfb)
{
    const int l  = threadIdx.x;
    const int nt = blockIdx.x & 7;
    const int kb = blockIdx.x >> 3;
    const int ly = blockIdx.y;
    const int n  = nt * 16 + (l & 15);
    const int k0 = kb * 32 + (l >> 4) * 8;
    H8 v;
    if (ly < 3) {
        const float* W = (ly == 0) ? Wa1 : (ly == 1) ? Wa2 : Wd;
        #pragma unroll
        for (int e = 0; e < 8; ++e) v.h[e] = (_Float16)W[(k0 + e) * DD + n];
        *(uint4*)(wfm + (size_t)(((ly * 8 + nt) * 4 + kb) * 64 + l) * 8) = v.q;
    } else {
        #pragma unroll
        for (int e = 0; e < 8; ++e) {
            float w = (n < 64) ? Wk[(k0 + e) * DH + n] : Wq[(k0 + e) * DH + n - 64];
            v.h[e] = (_Float16)w;
        }
        *(uint4*)(wfb + (size_t)((nt * 4 + kb) * 64 + l) * 8) = v.q;
    }
}

// ---------------------------------------------------------------------------
// Kernel 1: binding logits via fp16 MFMA, 2-product, inline fp32 fixup.
// (r19 version: launch_bounds(256,4) + async B DMA)
// ---------------------------------------------------------------------------
__global__ __launch_bounds__(256, 4) void k_bind(
    const float* __restrict__ x, const ushort* __restrict__ wfb,
    const float* __restrict__ Wk, const float* __restrict__ Wq,
    const float* __restrict__ bk, const float* __restrict__ bq,
    int* __restrict__ cstart)
{
    __shared__ uint4 Bs4[2048];
    __shared__ float bnd[4][64];
    const int b    = blockIdx.y;
    const int tb   = blockIdx.x * 64;
    const int tid  = threadIdx.x;
    const int wv   = tid >> 6;
    const int l    = tid & 63;
    const int lo16 = l & 15;
    const int g    = l >> 4;

    {
        const uint4* wsrc = (const uint4*)wfb;
        #pragma unroll
        for (int j = 0; j < 8; ++j) {
            int idx = tid + j * 256;
            __builtin_amdgcn_global_load_lds(
                (const __attribute__((address_space(1))) void*)(wsrc + idx),
                (__attribute__((address_space(3))) void*)&Bs4[idx], 16, 0, 0);
        }
    }

    const float* xrow = x + ((size_t)b * TT + tb + wv * 16 + lo16) * DD;
    half8 xh[4], xl[4];
    #pragma unroll
    for (int kb = 0; kb < 4; ++kb) {
        float4 v0 = ld4(xrow + kb * 32 + g * 8);
        float4 v1 = ld4(xrow + kb * 32 + g * 8 + 4);
        split8h(v0, v1, &xh[kb], &xl[kb]);
    }
    int r64 = tb + 64; if (r64 > TT - 1) r64 = TT - 1;
    const float* xq = x + ((size_t)b * TT + r64) * DD;
    half8 qh[4], ql[4];
    H8 z; z.q.x = z.q.y = z.q.z = z.q.w = 0u;
    #pragma unroll
    for (int kb = 0; kb < 4; ++kb) {
        qh[kb] = z.h; ql[kb] = z.h;
        if (lo16 == 0) {
            float4 v0 = ld4(xq + kb * 32 + g * 8);
            float4 v1 = ld4(xq + kb * 32 + g * 8 + 4);
            split8h(v0, v1, &qh[kb], &ql[kb]);
        }
    }

    f32x4 acc[8];
    #pragma unroll
    for (int nt = 0; nt < 8; ++nt) {
        int col = nt * 16 + lo16;
        float bias = (col < 64) ? bk[col] : bq[col - 64];
        acc[nt] = (f32x4){bias, bias, bias, bias};
    }
    f32x4 acc4;
    {
        float bias = bq[wv * 16 + lo16];
        acc4 = (f32x4){bias, bias, bias, bias};
    }

    asm volatile("s_waitcnt vmcnt(0)" ::: "memory");
    __syncthreads();
    const ushort* Bs = (const ushort*)Bs4;
    const ushort* Bs_halo = Bs + (size_t)((4 + wv) * 4 * 64 + l) * 8;
    #pragma unroll
    for (int kb = 0; kb < 4; ++kb) {
        half8 bh[8];
        #pragma unroll
        for (int nt = 0; nt < 8; ++nt)
            bh[nt] = *(const half8*)(Bs + (size_t)((nt * 4 + kb) * 64 + l) * 8);
        #pragma unroll
        for (int nt = 0; nt < 8; ++nt) {
            acc[nt] = __builtin_amdgcn_mfma_f32_16x16x32_f16(xh[kb], bh[nt], acc[nt], 0, 0, 0);
            acc[nt] = __builtin_amdgcn_mfma_f32_16x16x32_f16(xl[kb], bh[nt], acc[nt], 0, 0, 0);
        }
        half8 bh4 = *(const half8*)(Bs_halo + (size_t)kb * 64 * 8);
        acc4 = __builtin_amdgcn_mfma_f32_16x16x32_f16(qh[kb], bh4, acc4, 0, 0, 0);
        acc4 = __builtin_amdgcn_mfma_f32_16x16x32_f16(ql[kb], bh4, acc4, 0, 0, 0);
    }

    if (l < 16) {
        if (wv > 0) {
            #pragma unroll
            for (int nt = 0; nt < 4; ++nt) bnd[wv - 1][nt * 16 + lo16] = acc[4 + nt][0];
        }
        bnd[3][wv * 16 + lo16] = acc4[0];
    }
    __syncthreads();

    float qn3[4];
    #pragma unroll
    for (int nt = 0; nt < 4; ++nt) qn3[nt] = __shfl_down(acc[4 + nt][0], 16);
    if (g == 3) {
        #pragma unroll
        for (int nt = 0; nt < 4; ++nt) qn3[nt] = bnd[wv][nt * 16 + lo16];
    }
    float s[4];
    #pragma unroll
    for (int i = 0; i < 3; ++i) {
        float t = 0.f;
        #pragma unroll
        for (int nt = 0; nt < 4; ++nt) t += acc[nt][i] * acc[4 + nt][i + 1];
        s[i] = t;
    }
    {
        float t = 0.f;
        #pragma unroll
        for (int nt = 0; nt < 4; ++nt) t += acc[nt][3] * qn3[nt];
        s[3] = t;
    }
    #pragma unroll
    for (int i = 0; i < 4; ++i) {
        #pragma unroll
        for (int m = 1; m < 16; m <<= 1) s[i] += __shfl_xor(s[i], m);
    }

    #pragma unroll
    for (int i = 0; i < 4; ++i) {
        int t = tb + wv * 16 + g * 4 + i;
        bool valid = (lo16 == 0) && (t <= TT - 2);
        bool border = valid && (fabsf(s[i]) < FMARGIN);
        if (valid && !border) cstart[b * TT + t + 1] = (s[i] > 0.f) ? 0 : 1;
        unsigned long long m = __ballot(border);
        while (m) {
            int src = __ffsll((long long)m) - 1;
            m &= m - 1;
            int tf = tb + wv * 16 + (src >> 4) * 4 + i;
            const float* xt = x + ((size_t)b * TT + tf) * DD;
            float K = bk[l], Q = bq[l];
            #pragma unroll 8
            for (int k2 = 0; k2 < DD; ++k2) {
                K = fmaf(xt[k2],      Wk[k2 * DH + l], K);
                Q = fmaf(xt[DD + k2], Wq[k2 * DH + l], Q);
            }
            float p = K * Q;
            #pragma unroll
            for (int m2 = 1; m2 < 64; m2 <<= 1) p += __shfl_xor(p, m2);
            if (l == 0) cstart[b * TT + tf + 1] = (p > 0.f) ? 0 : 1;
        }
    }
    if (blockIdx.x == 0 && tid == 0) cstart[b * TT] = 1;
}

// ---------------------------------------------------------------------------
// Kernel 2: per-batch scan -> seg, chunk-start table, counts. (unchanged)
// ---------------------------------------------------------------------------
__global__ __launch_bounds__(1024) void k_scan(const int* __restrict__ cstart,
    int* __restrict__ seg, int* __restrict__ cs, int* __restrict__ numC)
{
    __shared__ int wsum[16];
    const int b = blockIdx.x, tid = threadIdx.x;
    const int wv = tid >> 6, lane = tid & 63;
    const int base = b * TT + tid * 16;
    int v[16];
    #pragma unroll
    for (int i = 0; i < 4; ++i) {
        int4 q = *(const int4*)(cstart + base + i * 4);
        v[i * 4 + 0] = q.x; v[i * 4 + 1] = q.y; v[i * 4 + 2] = q.z; v[i * 4 + 3] = q.w;
    }
    int s[16]; int run = 0;
    #pragma unroll
    for (int i = 0; i < 16; ++i) { run += v[i]; s[i] = run; }
    int incl = run;
    #pragma unroll
    for (int off = 1; off < 64; off <<= 1) {
        int t = __shfl_up(incl, off);
        if (lane >= off) incl += t;
    }
    if (lane == 63) wsum[wv] = incl;
    __syncthreads();
    if (tid < 16) {
        int w = wsum[tid];
        #pragma unroll
        for (int off = 1; off < 16; off <<= 1) {
            int t = __shfl_up(w, off, 16);
            if (tid >= off) w += t;
        }
        wsum[tid] = w;
    }
    __syncthreads();
    const int excl = (wv ? wsum[wv - 1] : 0) + incl - run;
    #pragma unroll
    for (int i = 0; i < 16; ++i) {
        int sg = excl + s[i] - 1;
        seg[base + i] = sg;
        if (v[i]) cs[b * (TT + 1) + sg] = tid * 16 + i;
    }
    if (tid == 1023) {
        int tot = excl + run;
        numC[b] = tot;
        cs[b * (TT + 1) + tot] = TT;
    }
}

// ---------------------------------------------------------------------------
// k_mlp GEMM: acc[8] = A(fp16 frags in LDS) @ B(fp16 frags in LDS).
// ---------------------------------------------------------------------------
__device__ __forceinline__ void mlp_gemm(f32x4 acc[8], const uint4* Afr4,
    const ushort* Bs, int wv, int l)
{
    half8 af[4];
    #pragma unroll
    for (int kb = 0; kb < 4; ++kb)
        af[kb] = *(const half8*)((const char*)Afr4 + ((wv * 4 + kb) * 64 + l) * 16);
    #pragma unroll
    for (int kb = 0; kb < 4; ++kb) {
        half8 bh[8];
        #pragma unroll
        for (int nt = 0; nt < 8; ++nt)
            bh[nt] = *(const half8*)(Bs + (size_t)((nt * 4 + kb) * 64 + l) * 8);
        #pragma unroll
        for (int nt = 0; nt < 8; ++nt)
            acc[nt] = __builtin_amdgcn_mfma_f32_16x16x32_f16(af[kb], bh[nt], acc[nt], 0, 0, 0);
    }
}

// ---------------------------------------------------------------------------
// Kernel 3: per-chunk MLP via fp16 MFMA. (r19 version: 64 chunks/block,
// async-DMA dbuf phase 1 with sequential per-slot reduce; async B DMAs.)
// ---------------------------------------------------------------------------
__global__ __launch_bounds__(256, 2) void k_mlp(
    const float* __restrict__ x, const int* __restrict__ cs,
    const float* __restrict__ ba1, const float* __restrict__ ln_g, const float* __restrict__ ln_b,
    const float* __restrict__ ba2, const float* __restrict__ bd,
    const ushort* __restrict__ wfm, const int* __restrict__ numC, float* __restrict__ cm)
{
    __shared__ union {
        float Tok[2][32 * 128];                            // 2 x 16384 B (UNPADDED: DMA dest)
        struct { uint4 Afr[1024]; uint4 Bs[2048]; } fb;    // 49152 B frags
    } sm;
    const int b  = blockIdx.y;
    const int nC = numC[b];
    const int c0 = blockIdx.x * 64;
    if (c0 >= nC) return;
    const int tid  = threadIdx.x;
    const int wv   = tid >> 6;
    const int l    = tid & 63;
    const int lo16 = l & 15;
    const int g    = l >> 4;
    const ushort* Bs = (const ushort*)sm.fb.Bs;
    const uint4* wsrc = (const uint4*)wfm;

    // ---- phase 1: chunk means, async double-buffered 32-token tiles ----
    const int cbase = b * (TT + 1);
    const int T0 = cs[cbase + c0];
    const int cEnd = (c0 + 64 < nC) ? (c0 + 64) : nC;
    const int T1 = cs[cbase + cEnd];
    int t0r[8], t1r[8];
    #pragma unroll
    for (int ii = 0; ii < 8; ++ii) {
        int r = (tid + ii * 256) >> 5;
        int c = c0 + r;
        t0r[ii] = (c < nC) ? cs[cbase + c] : 0;
        t1r[ii] = (c < nC) ? cs[cbase + c + 1] : 0;
    }
    float4 vals[8];
    #pragma unroll
    for (int ii = 0; ii < 8; ++ii) vals[ii] = make_float4(0.f, 0.f, 0.f, 0.f);

    // prologue: async-stage tile 0 into Tok[0]
    {
        const int n16 = ((T0 + 32 < T1) ? 32 : (T1 - T0)) * 32;
        #pragma unroll
        for (int j = 0; j < 4; ++j) {
            int base16 = j * 256 + wv * 64;
            if (base16 + l < n16) {
                const float* gs = x + ((size_t)b * TT + T0) * DD + (size_t)(base16 + l) * 4;
                __builtin_amdgcn_global_load_lds(
                    (const __attribute__((address_space(1))) void*)gs,
                    (__attribute__((address_space(3))) void*)&sm.Tok[0][base16 * 4],
                    16, 0, 0);
            }
        }
    }
    int buf = 0;
    for (int tt = T0; tt < T1; tt += 32) {
        asm volatile("s_waitcnt vmcnt(0)" ::: "memory");
        __syncthreads();
        const int tEnd = (tt + 32 < T1) ? (tt + 32) : T1;
        if (tt + 32 < T1) {
            const int nEnd = (tt + 64 < T1) ? (tt + 64) : T1;
            const int n16 = (nEnd - (tt + 32)) * 32;
            #pragma unroll
            for (int j = 0; j < 4; ++j) {
                int base16 = j * 256 + wv * 64;
                if (base16 + l < n16) {
                    const float* gs = x + ((size_t)b * TT + tt + 32) * DD + (size_t)(base16 + l) * 4;
                    __builtin_amdgcn_global_load_lds(
                        (const __attribute__((address_space(1))) void*)gs,
                        (__attribute__((address_space(3))) void*)&sm.Tok[buf ^ 1][base16 * 4],
                        16, 0, 0);
                }
            }
        }
        #pragma unroll
        for (int ii = 0; ii < 8; ++ii) {
            int c4 = ((tid + ii * 256) & 31) * 4;
            int lo = (t0r[ii] > tt)   ? t0r[ii] : tt;
            int hi = (t1r[ii] < tEnd) ? t1r[ii] : tEnd;
            for (int t = lo; t < hi; ++t) {
                const float* ap = &sm.Tok[buf][(t - tt) * 128 + c4];
                vals[ii].x += ap[0]; vals[ii].y += ap[1];
                vals[ii].z += ap[2]; vals[ii].w += ap[3];
            }
        }
        buf ^= 1;
    }
    asm volatile("s_waitcnt vmcnt(0)" ::: "memory");
    __syncthreads();

    // issue B0 DMA (overlaps the A-frag pack below)
    #pragma unroll
    for (int j = 0; j < 8; ++j) {
        int idx = tid + j * 256;
        __builtin_amdgcn_global_load_lds(
            (const __attribute__((address_space(1))) void*)(wsrc + idx),
            (__attribute__((address_space(3))) void*)&sm.fb.Bs[idx], 16, 0, 0);
    }
    #pragma unroll
    for (int ii = 0; ii < 8; ++ii) {
        int i = tid + ii * 256;
        int r = i >> 5, c4 = (i & 31) * 4;
        float4 sv = make_float4(0.f, 0.f, 0.f, 0.f);
        if (c0 + r < nC) {
            float inv = 1.f / (float)(t1r[ii] - t0r[ii]);
            sv.x = vals[ii].x * inv; sv.y = vals[ii].y * inv;
            sv.z = vals[ii].z * inv; sv.w = vals[ii].w * inv;
        }
        int frag = (r >> 4) * 4 + (c4 >> 5);
        int lanef = (r & 15) + (((c4 & 31) >> 3) * 16);
        uint2 pk = make_uint2(pk2(sv.x, sv.y), pk2(sv.z, sv.w));
        *(uint2*)((char*)sm.fb.Afr + frag * 1024 + lanef * 16 + (c4 & 7) * 2) = pk;
    }
    asm volatile("s_waitcnt vmcnt(0)" ::: "memory");
    __syncthreads();

    // ---- layer 1 ----
    f32x4 acc[8];
    #pragma unroll
    for (int nt = 0; nt < 8; ++nt) {
        float bias = ba1[nt * 16 + lo16];
        acc[nt] = (f32x4){bias, bias, bias, bias};
    }
    mlp_gemm(acc, sm.fb.Afr, Bs, wv, l);

    float mu_[4], rs_[4];
    #pragma unroll
    for (int i = 0; i < 4; ++i) {
        float smv = 0.f;
        #pragma unroll
        for (int nt = 0; nt < 8; ++nt) smv += acc[nt][i];
        #pragma unroll
        for (int k = 1; k < 16; k <<= 1) smv += __shfl_xor(smv, k, 16);
        mu_[i] = smv * (1.f / 128.f);
        float vs = 0.f;
        #pragma unroll
        for (int nt = 0; nt < 8; ++nt) { float d = acc[nt][i] - mu_[i]; vs += d * d; }
        #pragma unroll
        for (int k = 1; k < 16; k <<= 1) vs += __shfl_xor(vs, k, 16);
        rs_[i] = rsqrtf(vs * (1.f / 128.f) + 1e-5f);
    }
    float gam[8], bet[8];
    #pragma unroll
    for (int nt = 0; nt < 8; ++nt) { gam[nt] = ln_g[nt * 16 + lo16]; bet[nt] = ln_b[nt * 16 + lo16]; }

    __syncthreads();
    #pragma unroll
    for (int j = 0; j < 8; ++j) {
        int idx = tid + j * 256;
        __builtin_amdgcn_global_load_lds(
            (const __attribute__((address_space(1))) void*)(wsrc + 2048 + idx),
            (__attribute__((address_space(3))) void*)&sm.fb.Bs[idx], 16, 0, 0);
    }
    #pragma unroll
    for (int nt = 0; nt < 8; ++nt) {
        int cw = nt * 16 + lo16;
        int frag = wv * 4 + (cw >> 5);
        int lnf  = (((cw & 31) >> 3) * 16);
        #pragma unroll
        for (int i = 0; i < 4; ++i) {
            float h = fmaf((acc[nt][i] - mu_[i]) * rs_[i], gam[nt], bet[nt]);
            union { _Float16 f; ushort u; } cv; cv.f = (_Float16)fmaxf(h, 0.f);
            *((ushort*)((char*)sm.fb.Afr + frag * 1024 + ((g * 4 + i) + lnf) * 16 + (cw & 7) * 2)) = cv.u;
        }
    }
    asm volatile("s_waitcnt vmcnt(0)" ::: "memory");
    __syncthreads();

    // ---- layer 2 ----
    #pragma unroll
    for (int nt = 0; nt < 8; ++nt) {
        float bias = ba2[nt * 16 + lo16];
        acc[nt] = (f32x4){bias, bias, bias, bias};
    }
    mlp_gemm(acc, sm.fb.Afr, Bs, wv, l);
    __syncthreads();
    #pragma unroll
    for (int j = 0; j < 8; ++j) {
        int idx = tid + j * 256;
        __builtin_amdgcn_global_load_lds(
            (const __attribute__((address_space(1))) void*)(wsrc + 4096 + idx),
            (__attribute__((address_space(3))) void*)&sm.fb.Bs[idx], 16, 0, 0);
    }
    #pragma unroll
    for (int nt = 0; nt < 8; ++nt) {
        int cw = nt * 16 + lo16;
        int frag = wv * 4 + (cw >> 5);
        int lnf  = (((cw & 31) >> 3) * 16);
        #pragma unroll
        for (int i = 0; i < 4; ++i) {
            union { _Float16 f; ushort u; } cv; cv.f = (_Float16)acc[nt][i];
            *((ushort*)((char*)sm.fb.Afr + frag * 1024 + ((g * 4 + i) + lnf) * 16 + (cw & 7) * 2)) = cv.u;
        }
    }
    asm volatile("s_waitcnt vmcnt(0)" ::: "memory");
    __syncthreads();

    // ---- layer 3: gate = sigmoid -> cm (fp32) ----
    #pragma unroll
    for (int nt = 0; nt < 8; ++nt) {
        float bias = bd[nt * 16 + lo16];
        acc[nt] = (f32x4){bias, bias, bias, bias};
    }
    mlp_gemm(acc, sm.fb.Afr, Bs, wv, l);
    #pragma unroll
    for (int i = 0; i < 4; ++i) {
        int row = c0 + wv * 16 + g * 4 + i;
        if (row < nC) {
            float* dst = cm + ((size_t)b * TT + row) * DD + lo16;
            #pragma unroll
            for (int nt = 0; nt < 8; ++nt)
                dst[nt * 16] = 1.f / (1.f + __expf(-acc[nt][i]));
        }
    }
}

// ---------------------------------------------------------------------------
// Kernel 4: out[t] = fma(x[t], gate[seg[t]], x[t])
// ---------------------------------------------------------------------------
__global__ __launch_bounds__(256) void k_out(const float* __restrict__ x,
    const int* __restrict__ seg, const float* __restrict__ gate, float* __restrict__ out)
{
    const size_t idx = (size_t)blockIdx.x * 256 + threadIdx.x;
    const size_t tok = idx >> 5;
    const int d4 = (int)(idx & 31);
    const int b  = (int)(tok >> 14);
    const int sg = seg[tok];
    float4 gv = ld4(gate + (((size_t)b << 14) + sg) * DD + d4 * 4);
    float4 xv = ld4(x + tok * DD + (size_t)d4 * 4);
    float4 o;
    o.x = fmaf(xv.x, gv.x, xv.x);
    o.y = fmaf(xv.y, gv.y, xv.y);
    o.z = fmaf(xv.z, gv.z, xv.z);
    o.w = fmaf(xv.w, gv.w, xv.w);
    *(float4*)(out + idx * 4) = o;
}

extern "C" void kernel_launch(void* const* d_in, const int* in_sizes, int n_in,
                              void* d_out, int out_size, void* d_ws, size_t ws_size,
                              hipStream_t stream)
{
    (void)in_sizes; (void)n_in; (void)out_size; (void)ws_size;
    const float* x    = (const float*)d_in[0];
    const float* Wk   = (const float*)d_in[1];
    const float* bk   = (const float*)d_in[2];
    const float* Wq   = (const float*)d_in[3];
    const float* bq   = (const float*)d_in[4];
    const float* Wa1  = (const float*)d_in[5];
    const float* ba1  = (const float*)d_in[6];
    const float* ln_g = (const float*)d_in[7];
    const float* ln_b = (const float*)d_in[8];
    const float* Wa2  = (const float*)d_in[9];
    const float* ba2  = (const float*)d_in[10];
    const float* Wd   = (const float*)d_in[11];
    const float* bd   = (const float*)d_in[12];
    float* out = (float*)d_out;

    // ws layout
    char* p = (char*)d_ws;
    float* cm    = (float*)p;   p += (size_t)BB * TT * DD * 4;   // 64 MB (means -> gate)
    int* seg     = (int*)p;     p += (size_t)BB * TT * 4;        // bind bits -> seg ids
    int* cs      = (int*)p;     p += (size_t)BB * (TT + 1) * 4;
    int* numC    = (int*)p;     p += 64;
    ushort* wfm  = (ushort*)p;  p += 3 * DD * DD * 2;            // MLP W frags fp16 (96 KB)
    ushort* wfb  = (ushort*)p;  p += DD * DD * 2;                // bind W frags fp16 (32 KB)

    k_wprep<<<dim3(32, 4), 64, 0, stream>>>(Wa1, Wa2, Wd, Wk, Wq, wfm, wfb);
    k_bind<<<dim3(256, BB), 256, 0, stream>>>(x, wfb, Wk, Wq, bk, bq, seg);
    k_scan<<<dim3(BB), 1024, 0, stream>>>(seg, seg, cs, numC);
    k_mlp<<<dim3(TT / 64, BB), 256, 0, stream>>>(x, cs, ba1, ln_g, ln_b, ba2, bd, wfm, numC, cm);
    k_out<<<dim3(BB * TT * DD / (256 * 4)), 256, 0, stream>>>(x, seg, cm, out);
}